// Round 1
// baseline (1135.788 us; speedup 1.0000x reference)
//
#include <hip/hip_runtime.h>

#define N_MET 250000
#define N_RXN 500000
#define E_SUB 2000000
#define E_ALL 4000000
#define DT 0.01f

#define SCAN_T 256
#define SCAN_V 8
#define SCAN_CHUNK (SCAN_T * SCAN_V)
#define SCAN_NB ((N_RXN + SCAN_CHUNK - 1) / SCAN_CHUNK)
static_assert(SCAN_NB <= SCAN_T, "scan2 single block must cover all block sums");

static __device__ __forceinline__ float fast_tanh(float x) {
  // tanh(x) = 1 - 2/(e^{2x}+1); saturates correctly for |x| large (inf -> 1, 0 -> -1)
  float e = __expf(x + x);
  return 1.0f - __fdividef(2.0f, e + 1.0f);
}

static __device__ __forceinline__ void atomic_add_f32(float* p, float v) {
  __hip_atomic_fetch_add(p, v, __ATOMIC_RELAXED, __HIP_MEMORY_SCOPE_AGENT);
}

// ---- precompute W23[j][i] (transposed: row j = output dim) and b2@W3 ----
__global__ void k_pre(const float* __restrict__ W2, const float* __restrict__ W3,
                      const float* __restrict__ b2, float* __restrict__ Wt,
                      float* __restrict__ b2w3) {
  int idx = blockIdx.x * blockDim.x + threadIdx.x;  // 0..4095
  if (idx < 4096) {
    int j = idx >> 6, i = idx & 63;
    float s = 0.f;
    #pragma unroll
    for (int k = 0; k < 32; ++k) s = fmaf(W2[i * 32 + k], W3[k * 64 + j], s);
    Wt[j * 64 + i] = s;
    if (i == 0) {
      float t = 0.f;
      #pragma unroll
      for (int k = 0; k < 32; ++k) t = fmaf(b2[k], W3[k * 64 + j], t);
      b2w3[j] = t;
    }
  }
}

// ---- CSR build ----
__global__ void k_hist(const int* __restrict__ rxn_sub, int* __restrict__ counts) {
  int e = blockIdx.x * blockDim.x + threadIdx.x;
  if (e < E_SUB) atomicAdd(&counts[rxn_sub[e]], 1);
}

__global__ void k_scan1(const int* __restrict__ counts, int* __restrict__ bsums) {
  __shared__ int ss[SCAN_T];
  int b = blockIdx.x, t = threadIdx.x;
  int base = b * SCAN_CHUNK + t * SCAN_V;
  int s = 0;
  #pragma unroll
  for (int k = 0; k < SCAN_V; ++k) { int i = base + k; if (i < N_RXN) s += counts[i]; }
  ss[t] = s; __syncthreads();
  for (int d = SCAN_T / 2; d > 0; d >>= 1) {
    if (t < d) ss[t] += ss[t + d];
    __syncthreads();
  }
  if (t == 0) bsums[b] = ss[0];
}

__global__ void k_scan2(int* __restrict__ bsums) {
  __shared__ int ss[SCAN_T];
  int t = threadIdx.x;
  int v = (t < SCAN_NB) ? bsums[t] : 0;
  ss[t] = v; __syncthreads();
  for (int d = 1; d < SCAN_T; d <<= 1) {
    int a = (t >= d) ? ss[t - d] : 0;
    __syncthreads();
    ss[t] += a;
    __syncthreads();
  }
  if (t < SCAN_NB) bsums[t] = ss[t] - v;  // exclusive
}

__global__ void k_scan3(const int* __restrict__ counts, const int* __restrict__ bsums,
                        int* __restrict__ off, int* __restrict__ cursor) {
  __shared__ int ss[SCAN_T];
  int b = blockIdx.x, t = threadIdx.x;
  int base = b * SCAN_CHUNK + t * SCAN_V;
  int v[SCAN_V];
  int s = 0;
  #pragma unroll
  for (int k = 0; k < SCAN_V; ++k) { int i = base + k; v[k] = (i < N_RXN) ? counts[i] : 0; s += v[k]; }
  ss[t] = s; __syncthreads();
  for (int d = 1; d < SCAN_T; d <<= 1) {
    int a = (t >= d) ? ss[t - d] : 0;
    __syncthreads();
    ss[t] += a;
    __syncthreads();
  }
  int run = bsums[b] + ss[t] - s;  // global exclusive offset of this thread's chunk
  #pragma unroll
  for (int k = 0; k < SCAN_V; ++k) {
    int i = base + k;
    if (i < N_RXN) { off[i] = run; cursor[i] = run; }
    run += v[k];
  }
  if (b == 0 && t == 0) off[N_RXN] = E_SUB;
}

__global__ void k_scatter(const int* __restrict__ rxn_sub, int* __restrict__ cursor,
                          int* __restrict__ eids) {
  int e = blockIdx.x * blockDim.x + threadIdx.x;
  if (e < E_SUB) {
    int pos = atomicAdd(&cursor[rxn_sub[e]], 1);
    eids[pos] = e;
  }
}

// ---- per-reaction: edge tanh-sum, matvec via W23, v_pre; fused consumption atomics ----
__global__ __launch_bounds__(256) void k_rxn(
    const int* __restrict__ off, const int* __restrict__ eids,
    const int* __restrict__ met_sub, const float* __restrict__ sto_sub,
    const float* __restrict__ x,
    const float* __restrict__ W1, const float* __restrict__ b1,
    const float* __restrict__ Wt, const float* __restrict__ b2w3,
    const float* __restrict__ b3, const float* __restrict__ W4,
    const float* __restrict__ b4, const float* __restrict__ log_k,
    float* __restrict__ v_pre, float* __restrict__ total) {
  __shared__ float4 sW1[64];    // (W1[0][j], W1[1][j], b1[j], -)
  __shared__ float4 sB[64];     // (b2w3[j], b3[j], W4[j], -)
  __shared__ float4 sWt[1024];  // W23 transposed, row j contiguous
  int t = threadIdx.x;
  if (t < 64) {
    sW1[t] = make_float4(W1[t], W1[64 + t], b1[t], 0.f);
    sB[t] = make_float4(b2w3[t], b3[t], W4[t], 0.f);
  }
  const float4* Wt4 = (const float4*)Wt;
  for (int i = t; i < 1024; i += 256) sWt[i] = Wt4[i];
  __syncthreads();

  int r = blockIdx.x * 256 + t;
  if (r >= N_RXN) return;
  int o0 = off[r], o1 = off[r + 1];

  float T[64];
  #pragma unroll
  for (int j = 0; j < 64; ++j) T[j] = 0.f;

  for (int c = o0; c < o1; ++c) {
    int e = eids[c];
    int m = met_sub[e];
    float s = sto_sub[e];
    float cc = x[m * 8 + 3];
    #pragma unroll
    for (int j = 0; j < 64; ++j) {
      float4 w = sW1[j];
      float h = fmaf(cc, w.x, fmaf(s, w.y, w.z));
      T[j] += fast_tanh(h);
    }
  }

  float n = (float)(o1 - o0);
  float racc = b4[0];
  #pragma unroll 8
  for (int j = 0; j < 64; ++j) {
    float4 meta = sB[j];
    float a0 = fmaf(n, meta.x, meta.y), a1 = 0.f, a2 = 0.f, a3 = 0.f;
    #pragma unroll
    for (int q = 0; q < 16; ++q) {
      float4 w = sWt[j * 16 + q];
      a0 = fmaf(T[4 * q + 0], w.x, a0);
      a1 = fmaf(T[4 * q + 1], w.y, a1);
      a2 = fmaf(T[4 * q + 2], w.z, a2);
      a3 = fmaf(T[4 * q + 3], w.w, a3);
    }
    float u = (a0 + a1) + (a2 + a3);
    racc = fmaf(fast_tanh(u), meta.z, racc);
  }

  float k10 = __expf(log_k[r] * 2.3025850929940457f);        // 10^log_k
  float sp = (racc > 15.f) ? racc : __logf(1.f + __expf(racc));  // softplus
  float v = k10 * sp;
  v_pre[r] = v;

  float vdt = v * DT;
  for (int c = o0; c < o1; ++c) {
    int e = eids[c];
    atomic_add_f32(&total[met_sub[e]], sto_sub[e] * vdt);
  }
}

__global__ void k_scale(const float* __restrict__ total, const float* __restrict__ x,
                        float* __restrict__ met_scale) {
  int m = blockIdx.x * blockDim.x + threadIdx.x;
  if (m < N_MET) {
    float tot = total[m];
    float cc = x[m * 8 + 3];
    met_scale[m] = (tot > 1e-12f) ? fminf(cc / tot, 1.0f) : 1.0f;
  }
}

__global__ void k_vfin(const int* __restrict__ off, const int* __restrict__ eids,
                       const int* __restrict__ met_sub, const float* __restrict__ met_scale,
                       const float* __restrict__ v_pre, float* __restrict__ v_fin) {
  int r = blockIdx.x * blockDim.x + threadIdx.x;
  if (r < N_RXN) {
    int o0 = off[r], o1 = off[r + 1];
    float sc = 1.0f;
    for (int c = o0; c < o1; ++c) sc = fminf(sc, met_scale[met_sub[eids[c]]]);
    v_fin[r] = v_pre[r] * sc;
  }
}

__global__ void k_contrib(const int* __restrict__ met_all, const int* __restrict__ rxn_all,
                          const float* __restrict__ sto_all, const float* __restrict__ v_fin,
                          float* __restrict__ dxdt) {
  int e = blockIdx.x * blockDim.x + threadIdx.x;
  if (e < E_ALL) {
    atomic_add_f32(&dxdt[met_all[e]], sto_all[e] * v_fin[rxn_all[e]]);
  }
}

extern "C" void kernel_launch(void* const* d_in, const int* in_sizes, int n_in,
                              void* d_out, int out_size, void* d_ws, size_t ws_size,
                              hipStream_t stream) {
  const float* x       = (const float*)d_in[0];
  const int*   met_sub = (const int*)d_in[1];
  const int*   rxn_sub = (const int*)d_in[2];
  const float* sto_sub = (const float*)d_in[3];
  const int*   met_all = (const int*)d_in[4];
  const int*   rxn_all = (const int*)d_in[5];
  const float* sto_all = (const float*)d_in[6];
  const float* W1    = (const float*)d_in[7];
  const float* b1    = (const float*)d_in[8];
  const float* W2    = (const float*)d_in[9];
  const float* b2    = (const float*)d_in[10];
  const float* W3    = (const float*)d_in[11];
  const float* b3    = (const float*)d_in[12];
  const float* W4    = (const float*)d_in[13];
  const float* b4    = (const float*)d_in[14];
  const float* log_k = (const float*)d_in[15];
  float* dxdt = (float*)d_out;

  char* ws = (char*)d_ws;
  size_t p = 0;
  auto alloc = [&](size_t bytes) -> void* {
    void* r = (void*)(ws + p);
    p += (bytes + 255) & ~(size_t)255;
    return r;
  };
  int*   counts    = (int*)alloc(sizeof(int) * N_RXN);
  int*   off       = (int*)alloc(sizeof(int) * (N_RXN + 1));
  int*   cursor    = (int*)alloc(sizeof(int) * N_RXN);
  int*   eids      = (int*)alloc(sizeof(int) * E_SUB);
  int*   bsums     = (int*)alloc(sizeof(int) * 1024);
  float* Wt        = (float*)alloc(sizeof(float) * 4096);
  float* b2w3      = (float*)alloc(sizeof(float) * 64);
  float* v_pre     = (float*)alloc(sizeof(float) * N_RXN);
  float* v_fin     = (float*)alloc(sizeof(float) * N_RXN);
  float* total     = (float*)alloc(sizeof(float) * N_MET);
  float* met_scale = (float*)alloc(sizeof(float) * N_MET);
  (void)ws_size; (void)in_sizes; (void)n_in; (void)out_size;

  hipMemsetAsync(counts, 0, sizeof(int) * N_RXN, stream);
  hipMemsetAsync(total, 0, sizeof(float) * N_MET, stream);
  hipMemsetAsync(dxdt, 0, sizeof(float) * N_MET, stream);

  k_pre<<<16, 256, 0, stream>>>(W2, W3, b2, Wt, b2w3);
  k_hist<<<(E_SUB + 255) / 256, 256, 0, stream>>>(rxn_sub, counts);
  k_scan1<<<SCAN_NB, SCAN_T, 0, stream>>>(counts, bsums);
  k_scan2<<<1, SCAN_T, 0, stream>>>(bsums);
  k_scan3<<<SCAN_NB, SCAN_T, 0, stream>>>(counts, bsums, off, cursor);
  k_scatter<<<(E_SUB + 255) / 256, 256, 0, stream>>>(rxn_sub, cursor, eids);
  k_rxn<<<(N_RXN + 255) / 256, 256, 0, stream>>>(off, eids, met_sub, sto_sub, x, W1, b1,
                                                 Wt, b2w3, b3, W4, b4, log_k, v_pre, total);
  k_scale<<<(N_MET + 255) / 256, 256, 0, stream>>>(total, x, met_scale);
  k_vfin<<<(N_RXN + 255) / 256, 256, 0, stream>>>(off, eids, met_sub, met_scale, v_pre, v_fin);
  k_contrib<<<(E_ALL + 255) / 256, 256, 0, stream>>>(met_all, rxn_all, sto_all, v_fin, dxdt);
}

// Round 2
// 990.452 us; speedup vs baseline: 1.1467x; 1.1467x over previous
//
#include <hip/hip_runtime.h>

#define N_MET 250000
#define N_RXN 500000
#define E_SUB 2000000
#define E_ALL 4000000
#define DT 0.01f

#define SCAN_T 256
#define SCAN_V 8
#define SCAN_CHUNK (SCAN_T * SCAN_V)
#define SCAN_NB ((N_RXN + SCAN_CHUNK - 1) / SCAN_CHUNK)
static_assert(SCAN_NB <= SCAN_T, "scan2 single block must cover all block sums");

static __device__ __forceinline__ float fast_tanh(float x) {
  float e = __expf(x + x);
  return 1.0f - __fdividef(2.0f, e + 1.0f);
}

static __device__ __forceinline__ void atomic_add_f32(float* p, float v) {
  __hip_atomic_fetch_add(p, v, __ATOMIC_RELAXED, __HIP_MEMORY_SCOPE_AGENT);
}

static __device__ __forceinline__ float lane_bcast(float v, int lane) {
  return __builtin_bit_cast(float, __builtin_amdgcn_readlane(__builtin_bit_cast(int, v), lane));
}

// ---- precompute W23t[j][i] = (W2@W3)[i][j] and b2@W3 ----
__global__ void k_pre(const float* __restrict__ W2, const float* __restrict__ W3,
                      const float* __restrict__ b2, float* __restrict__ Wt,
                      float* __restrict__ b2w3) {
  int idx = blockIdx.x * blockDim.x + threadIdx.x;  // 0..4095
  if (idx < 4096) {
    int j = idx >> 6, i = idx & 63;
    float s = 0.f;
    #pragma unroll
    for (int k = 0; k < 32; ++k) s = fmaf(W2[i * 32 + k], W3[k * 64 + j], s);
    Wt[j * 64 + i] = s;
    if (i == 0) {
      float t = 0.f;
      #pragma unroll
      for (int k = 0; k < 32; ++k) t = fmaf(b2[k], W3[k * 64 + j], t);
      b2w3[j] = t;
    }
  }
}

// ---- CSR build ----
__global__ void k_hist(const int* __restrict__ rxn_sub, int* __restrict__ counts) {
  int t = blockIdx.x * blockDim.x + threadIdx.x;
  if (t < E_SUB / 4) {
    int4 r = ((const int4*)rxn_sub)[t];
    atomicAdd(&counts[r.x], 1);
    atomicAdd(&counts[r.y], 1);
    atomicAdd(&counts[r.z], 1);
    atomicAdd(&counts[r.w], 1);
  }
}

__global__ void k_scan1(const int* __restrict__ counts, int* __restrict__ bsums) {
  __shared__ int ss[SCAN_T];
  int b = blockIdx.x, t = threadIdx.x;
  int base = b * SCAN_CHUNK + t * SCAN_V;
  int s = 0;
  #pragma unroll
  for (int k = 0; k < SCAN_V; ++k) { int i = base + k; if (i < N_RXN) s += counts[i]; }
  ss[t] = s; __syncthreads();
  for (int d = SCAN_T / 2; d > 0; d >>= 1) {
    if (t < d) ss[t] += ss[t + d];
    __syncthreads();
  }
  if (t == 0) bsums[b] = ss[0];
}

__global__ void k_scan2(int* __restrict__ bsums) {
  __shared__ int ss[SCAN_T];
  int t = threadIdx.x;
  int v = (t < SCAN_NB) ? bsums[t] : 0;
  ss[t] = v; __syncthreads();
  for (int d = 1; d < SCAN_T; d <<= 1) {
    int a = (t >= d) ? ss[t - d] : 0;
    __syncthreads();
    ss[t] += a;
    __syncthreads();
  }
  if (t < SCAN_NB) bsums[t] = ss[t] - v;  // exclusive
}

__global__ void k_scan3(const int* __restrict__ counts, const int* __restrict__ bsums,
                        int* __restrict__ off, int* __restrict__ cursor) {
  __shared__ int ss[SCAN_T];
  int b = blockIdx.x, t = threadIdx.x;
  int base = b * SCAN_CHUNK + t * SCAN_V;
  int v[SCAN_V];
  int s = 0;
  #pragma unroll
  for (int k = 0; k < SCAN_V; ++k) { int i = base + k; v[k] = (i < N_RXN) ? counts[i] : 0; s += v[k]; }
  ss[t] = s; __syncthreads();
  for (int d = 1; d < SCAN_T; d <<= 1) {
    int a = (t >= d) ? ss[t - d] : 0;
    __syncthreads();
    ss[t] += a;
    __syncthreads();
  }
  int run = bsums[b] + ss[t] - s;
  #pragma unroll
  for (int k = 0; k < SCAN_V; ++k) {
    int i = base + k;
    if (i < N_RXN) { off[i] = run; cursor[i] = run; }
    run += v[k];
  }
  if (b == 0 && t == 0) off[N_RXN] = E_SUB;
}

// ---- scatter into CSR order, pre-gathering conc so k_rxn reads contiguous streams ----
__global__ void k_scatter(const int* __restrict__ rxn_sub, const int* __restrict__ met_sub,
                          const float* __restrict__ sto_sub, const float* __restrict__ x,
                          int* __restrict__ cursor, int* __restrict__ m_sorted,
                          float2* __restrict__ cs_sorted) {
  int e = blockIdx.x * blockDim.x + threadIdx.x;
  if (e < E_SUB) {
    int r = rxn_sub[e];
    int pos = atomicAdd(&cursor[r], 1);
    int m = met_sub[e];
    m_sorted[pos] = m;
    cs_sorted[pos] = make_float2(x[m * 8 + 3], sto_sub[e]);
  }
}

// ---- wave-per-reaction: lane j owns hidden dim j ----
__global__ __launch_bounds__(256) void k_rxn(
    const int* __restrict__ off, const int* __restrict__ m_sorted,
    const float2* __restrict__ cs_sorted,
    const float* __restrict__ W1, const float* __restrict__ b1,
    const float* __restrict__ Wt, const float* __restrict__ b2w3,
    const float* __restrict__ b3, const float* __restrict__ W4,
    const float* __restrict__ b4, const float* __restrict__ log_k,
    float* __restrict__ v_pre, float* __restrict__ total) {
  int lane = threadIdx.x & 63;
  int wid = blockIdx.x * (blockDim.x >> 6) + (threadIdx.x >> 6);
  int nw = gridDim.x * (blockDim.x >> 6);

  // per-lane parameters (lane j = hidden dim j)
  float w1x = W1[lane], w1y = W1[64 + lane], b1j = b1[lane];
  float bwj = b2w3[lane], b3j = b3[lane], w4j = W4[lane];
  float b40 = b4[0];
  float Wreg[64];  // row j of W23t, kept in VGPRs
  const float4* Wt4 = (const float4*)Wt;
  #pragma unroll
  for (int q = 0; q < 16; ++q) {
    float4 w = Wt4[lane * 16 + q];
    Wreg[4 * q + 0] = w.x; Wreg[4 * q + 1] = w.y;
    Wreg[4 * q + 2] = w.z; Wreg[4 * q + 3] = w.w;
  }

  for (int r = wid; r < N_RXN; r += nw) {
    int o0 = off[r], o1 = off[r + 1];

    // edge phase: all lanes walk the same edges (broadcast loads), zero divergence
    float T = 0.f;
    for (int c = o0; c < o1; ++c) {
      float2 cs = cs_sorted[c];
      T += fast_tanh(fmaf(cs.x, w1x, fmaf(cs.y, w1y, b1j)));
    }

    // matvec: u_j = n*b2w3_j + b3_j + sum_i T_i * W23t[j][i]
    float n = (float)(o1 - o0);
    float u = fmaf(n, bwj, b3j);
    #pragma unroll
    for (int i = 0; i < 64; ++i) {
      u = fmaf(lane_bcast(T, i), Wreg[i], u);
    }

    // z_j = tanh(u_j)*W4_j; butterfly-sum -> all lanes hold r-value
    float z = fast_tanh(u) * w4j;
    #pragma unroll
    for (int d = 32; d > 0; d >>= 1) z += __shfl_xor(z, d, 64);
    float racc = z + b40;

    float k10 = __expf(log_k[r] * 2.3025850929940457f);
    float sp = (racc > 15.f) ? racc : __logf(1.f + __expf(racc));
    float v = k10 * sp;
    if (lane == 0) v_pre[r] = v;

    // consumption atomics, lane-parallel
    float vdt = v * DT;
    for (int c = o0 + lane; c < o1; c += 64) {
      atomic_add_f32(&total[m_sorted[c]], cs_sorted[c].y * vdt);
    }
  }
}

__global__ void k_scale(const float* __restrict__ total, const float* __restrict__ x,
                        float* __restrict__ met_scale) {
  int m = blockIdx.x * blockDim.x + threadIdx.x;
  if (m < N_MET) {
    float tot = total[m];
    float cc = x[m * 8 + 3];
    met_scale[m] = (tot > 1e-12f) ? fminf(cc / tot, 1.0f) : 1.0f;
  }
}

__global__ void k_vfin(const int* __restrict__ off, const int* __restrict__ m_sorted,
                       const float* __restrict__ met_scale,
                       const float* __restrict__ v_pre, float* __restrict__ v_fin) {
  int r = blockIdx.x * blockDim.x + threadIdx.x;
  if (r < N_RXN) {
    int o0 = off[r], o1 = off[r + 1];
    float sc = 1.0f;
    for (int c = o0; c < o1; ++c) sc = fminf(sc, met_scale[m_sorted[c]]);
    v_fin[r] = v_pre[r] * sc;
  }
}

__global__ void k_contrib(const int* __restrict__ met_all, const int* __restrict__ rxn_all,
                          const float* __restrict__ sto_all, const float* __restrict__ v_fin,
                          float* __restrict__ dxdt) {
  int t = blockIdx.x * blockDim.x + threadIdx.x;
  if (t < E_ALL / 4) {
    int4 me = ((const int4*)met_all)[t];
    int4 re = ((const int4*)rxn_all)[t];
    float4 se = ((const float4*)sto_all)[t];
    atomic_add_f32(&dxdt[me.x], se.x * v_fin[re.x]);
    atomic_add_f32(&dxdt[me.y], se.y * v_fin[re.y]);
    atomic_add_f32(&dxdt[me.z], se.z * v_fin[re.z]);
    atomic_add_f32(&dxdt[me.w], se.w * v_fin[re.w]);
  }
}

extern "C" void kernel_launch(void* const* d_in, const int* in_sizes, int n_in,
                              void* d_out, int out_size, void* d_ws, size_t ws_size,
                              hipStream_t stream) {
  const float* x       = (const float*)d_in[0];
  const int*   met_sub = (const int*)d_in[1];
  const int*   rxn_sub = (const int*)d_in[2];
  const float* sto_sub = (const float*)d_in[3];
  const int*   met_all = (const int*)d_in[4];
  const int*   rxn_all = (const int*)d_in[5];
  const float* sto_all = (const float*)d_in[6];
  const float* W1    = (const float*)d_in[7];
  const float* b1    = (const float*)d_in[8];
  const float* W2    = (const float*)d_in[9];
  const float* b2    = (const float*)d_in[10];
  const float* W3    = (const float*)d_in[11];
  const float* b3    = (const float*)d_in[12];
  const float* W4    = (const float*)d_in[13];
  const float* b4    = (const float*)d_in[14];
  const float* log_k = (const float*)d_in[15];
  float* dxdt = (float*)d_out;

  char* ws = (char*)d_ws;
  size_t p = 0;
  auto alloc = [&](size_t bytes) -> void* {
    void* r = (void*)(ws + p);
    p += (bytes + 255) & ~(size_t)255;
    return r;
  };
  int*    counts    = (int*)alloc(sizeof(int) * N_RXN);
  int*    off       = (int*)alloc(sizeof(int) * (N_RXN + 1));
  int*    cursor    = (int*)alloc(sizeof(int) * N_RXN);
  int*    bsums     = (int*)alloc(sizeof(int) * 1024);
  float*  Wt        = (float*)alloc(sizeof(float) * 4096);
  float*  b2w3      = (float*)alloc(sizeof(float) * 64);
  float*  v_pre     = (float*)alloc(sizeof(float) * N_RXN);
  float*  v_fin     = (float*)alloc(sizeof(float) * N_RXN);
  float*  total     = (float*)alloc(sizeof(float) * N_MET);
  float*  met_scale = (float*)alloc(sizeof(float) * N_MET);
  int*    m_sorted  = (int*)alloc(sizeof(int) * E_SUB);
  float2* cs_sorted = (float2*)alloc(sizeof(float2) * E_SUB);
  (void)ws_size; (void)in_sizes; (void)n_in; (void)out_size;

  hipMemsetAsync(counts, 0, sizeof(int) * N_RXN, stream);
  hipMemsetAsync(total, 0, sizeof(float) * N_MET, stream);
  hipMemsetAsync(dxdt, 0, sizeof(float) * N_MET, stream);

  k_pre<<<16, 256, 0, stream>>>(W2, W3, b2, Wt, b2w3);
  k_hist<<<(E_SUB / 4 + 255) / 256, 256, 0, stream>>>(rxn_sub, counts);
  k_scan1<<<SCAN_NB, SCAN_T, 0, stream>>>(counts, bsums);
  k_scan2<<<1, SCAN_T, 0, stream>>>(bsums);
  k_scan3<<<SCAN_NB, SCAN_T, 0, stream>>>(counts, bsums, off, cursor);
  k_scatter<<<(E_SUB + 255) / 256, 256, 0, stream>>>(rxn_sub, met_sub, sto_sub, x,
                                                     cursor, m_sorted, cs_sorted);
  k_rxn<<<2048, 256, 0, stream>>>(off, m_sorted, cs_sorted, W1, b1, Wt, b2w3, b3, W4, b4,
                                  log_k, v_pre, total);
  k_scale<<<(N_MET + 255) / 256, 256, 0, stream>>>(total, x, met_scale);
  k_vfin<<<(N_RXN + 255) / 256, 256, 0, stream>>>(off, m_sorted, met_scale, v_pre, v_fin);
  k_contrib<<<(E_ALL / 4 + 255) / 256, 256, 0, stream>>>(met_all, rxn_all, sto_all, v_fin, dxdt);
}

// Round 3
// 948.558 us; speedup vs baseline: 1.1974x; 1.0442x over previous
//
#include <hip/hip_runtime.h>

#define N_MET 250000
#define N_RXN 500000
#define E_SUB 2000000
#define E_ALL 4000000
#define DT 0.01f

#define RXN_PER_BLK 256
#define EDGE_CAP 1792   // expected 1024 edges/block, sigma~32; fallback if exceeded

#define SCAN_T 256
#define SCAN_V 8
#define SCAN_CHUNK (SCAN_T * SCAN_V)
#define SCAN_NB ((N_RXN + SCAN_CHUNK - 1) / SCAN_CHUNK)
static_assert(SCAN_NB <= SCAN_T, "scan2 single block must cover all block sums");

static __device__ __forceinline__ float fast_tanh(float x) {
  float e = __expf(x + x);
  return 1.0f - __fdividef(2.0f, e + 1.0f);
}

static __device__ __forceinline__ void atomic_add_f32(float* p, float v) {
  __hip_atomic_fetch_add(p, v, __ATOMIC_RELAXED, __HIP_MEMORY_SCOPE_AGENT);
}

static __device__ __forceinline__ float bcast_f(float v, int lane) {
  return __builtin_bit_cast(float, __builtin_amdgcn_readlane(__builtin_bit_cast(int, v), lane));
}
static __device__ __forceinline__ int bcast_i(int v, int lane) {
  return __builtin_amdgcn_readlane(v, lane);
}

// ---- precompute W23t[j][i] = (W2@W3)[i][j] and b2@W3 ----
__global__ void k_pre(const float* __restrict__ W2, const float* __restrict__ W3,
                      const float* __restrict__ b2, float* __restrict__ Wt,
                      float* __restrict__ b2w3) {
  int idx = blockIdx.x * blockDim.x + threadIdx.x;
  if (idx < 4096) {
    int j = idx >> 6, i = idx & 63;
    float s = 0.f;
    #pragma unroll
    for (int k = 0; k < 32; ++k) s = fmaf(W2[i * 32 + k], W3[k * 64 + j], s);
    Wt[j * 64 + i] = s;
    if (i == 0) {
      float t = 0.f;
      #pragma unroll
      for (int k = 0; k < 32; ++k) t = fmaf(b2[k], W3[k * 64 + j], t);
      b2w3[j] = t;
    }
  }
}

// ---- CSR build ----
__global__ void k_hist(const int* __restrict__ rxn_sub, int* __restrict__ counts) {
  int t = blockIdx.x * blockDim.x + threadIdx.x;
  if (t < E_SUB / 4) {
    int4 r = ((const int4*)rxn_sub)[t];
    atomicAdd(&counts[r.x], 1);
    atomicAdd(&counts[r.y], 1);
    atomicAdd(&counts[r.z], 1);
    atomicAdd(&counts[r.w], 1);
  }
}

__global__ void k_scan1(const int* __restrict__ counts, int* __restrict__ bsums) {
  __shared__ int ss[SCAN_T];
  int b = blockIdx.x, t = threadIdx.x;
  int base = b * SCAN_CHUNK + t * SCAN_V;
  int s = 0;
  #pragma unroll
  for (int k = 0; k < SCAN_V; ++k) { int i = base + k; if (i < N_RXN) s += counts[i]; }
  ss[t] = s; __syncthreads();
  for (int d = SCAN_T / 2; d > 0; d >>= 1) {
    if (t < d) ss[t] += ss[t + d];
    __syncthreads();
  }
  if (t == 0) bsums[b] = ss[0];
}

__global__ void k_scan2(int* __restrict__ bsums) {
  __shared__ int ss[SCAN_T];
  int t = threadIdx.x;
  int v = (t < SCAN_NB) ? bsums[t] : 0;
  ss[t] = v; __syncthreads();
  for (int d = 1; d < SCAN_T; d <<= 1) {
    int a = (t >= d) ? ss[t - d] : 0;
    __syncthreads();
    ss[t] += a;
    __syncthreads();
  }
  if (t < SCAN_NB) bsums[t] = ss[t] - v;  // exclusive
}

__global__ void k_scan3(const int* __restrict__ counts, const int* __restrict__ bsums,
                        int* __restrict__ off, int* __restrict__ cursor,
                        float2* __restrict__ vr) {
  __shared__ int ss[SCAN_T];
  int b = blockIdx.x, t = threadIdx.x;
  int base = b * SCAN_CHUNK + t * SCAN_V;
  int v[SCAN_V];
  int s = 0;
  #pragma unroll
  for (int k = 0; k < SCAN_V; ++k) { int i = base + k; v[k] = (i < N_RXN) ? counts[i] : 0; s += v[k]; }
  ss[t] = s; __syncthreads();
  for (int d = 1; d < SCAN_T; d <<= 1) {
    int a = (t >= d) ? ss[t - d] : 0;
    __syncthreads();
    ss[t] += a;
    __syncthreads();
  }
  int run = bsums[b] + ss[t] - s;
  #pragma unroll
  for (int k = 0; k < SCAN_V; ++k) {
    int i = base + k;
    if (i < N_RXN) {
      off[i] = run; cursor[i] = run;
      vr[i] = make_float2(0.f, 1.0f);  // .y = scale accumulator (uint-min on positive floats)
    }
    run += v[k];
  }
  if (b == 0 && t == 0) off[N_RXN] = E_SUB;
}

// ---- scatter into CSR order, pre-gathering conc ----
__global__ void k_scatter(const int* __restrict__ rxn_sub, const int* __restrict__ met_sub,
                          const float* __restrict__ sto_sub, const float* __restrict__ x,
                          int* __restrict__ cursor, int* __restrict__ m_sorted,
                          float2* __restrict__ cs_sorted) {
  int e = blockIdx.x * blockDim.x + threadIdx.x;
  if (e < E_SUB) {
    int r = rxn_sub[e];
    int pos = atomicAdd(&cursor[r], 1);
    int m = met_sub[e];
    m_sorted[pos] = m;
    cs_sorted[pos] = make_float2(x[m * 8 + 3], sto_sub[e]);
  }
}

// Per-reaction body; csp/mp may point into LDS (fast path) or global (fallback).
// All edge indices are relative to estart.
template <typename CSP, typename MP>
static __device__ __forceinline__ void process_rxn(
    int i, int lane, int o0, int o1, int estart, CSP csp, MP mp,
    float w1x, float w1y, float b1j, float bwj, float b3j, float w4j, float b40,
    const float* Wreg, float lkl, float* vmine, float* __restrict__ total) {
  // edge phase: all lanes walk the same edges (LDS broadcast reads)
  float T = 0.f;
  for (int c = o0; c < o1; ++c) {
    float2 cs = csp[c - estart];
    T += fast_tanh(fmaf(cs.x, w1x, fmaf(cs.y, w1y, b1j)));
  }

  // matvec: u_j = n*b2w3_j + b3_j + sum_k T_k * W23t[j][k]
  float n = (float)(o1 - o0);
  float u = fmaf(n, bwj, b3j);
  #pragma unroll
  for (int k = 0; k < 64; ++k) u = fmaf(bcast_f(T, k), Wreg[k], u);

  float z = fast_tanh(u) * w4j;
  #pragma unroll
  for (int d = 32; d > 0; d >>= 1) z += __shfl_xor(z, d, 64);
  float racc = z + b40;

  float k10 = __expf(bcast_f(lkl, i) * 2.3025850929940457f);
  float sp = (racc > 15.f) ? racc : __logf(1.f + __expf(racc));
  float v = k10 * sp;
  *vmine = (lane == i) ? v : *vmine;

  float vdt = v * DT;
  for (int c = o0 + lane; c < o1; c += 64) {
    atomic_add_f32(&total[mp[c - estart]], csp[c - estart].y * vdt);
  }
}

// ---- wave-per-reaction with block-level LDS staging of the CSR slice ----
__global__ __launch_bounds__(256) void k_rxn(
    const int* __restrict__ off, const int* __restrict__ m_sorted,
    const float2* __restrict__ cs_sorted,
    const float* __restrict__ W1, const float* __restrict__ b1,
    const float* __restrict__ Wt, const float* __restrict__ b2w3,
    const float* __restrict__ b3, const float* __restrict__ W4,
    const float* __restrict__ b4, const float* __restrict__ log_k,
    float2* __restrict__ vr, float* __restrict__ total) {
  __shared__ int off_s[RXN_PER_BLK + 1];
  __shared__ float2 scs[EDGE_CAP];
  __shared__ int sm[EDGE_CAP];

  int tid = threadIdx.x;
  int lane = tid & 63;
  int wv = tid >> 6;
  int R0 = blockIdx.x * RXN_PER_BLK;

  // stage off slice
  for (int i = tid; i <= RXN_PER_BLK; i += 256) {
    int r = R0 + i;
    off_s[i] = off[r > N_RXN ? N_RXN : r];
  }
  __syncthreads();
  int estart = off_s[0];
  int nE = off_s[RXN_PER_BLK] - estart;
  bool fits = (nE <= EDGE_CAP);

  // stage edge slice (contiguous, coalesced)
  if (fits) {
    for (int i = tid; i < nE; i += 256) {
      scs[i] = cs_sorted[estart + i];
      sm[i] = m_sorted[estart + i];
    }
  }

  // per-lane parameters (lane j = hidden dim j)
  float w1x = W1[lane], w1y = W1[64 + lane], b1j = b1[lane];
  float bwj = b2w3[lane], b3j = b3[lane], w4j = W4[lane];
  float b40 = b4[0];
  // W row j in VGPRs, pinned so the compiler cannot sink the loads into the loop
  float Wreg[64];
  const float4* Wt4 = (const float4*)Wt;
  #pragma unroll
  for (int q = 0; q < 16; ++q) {
    float4 w = Wt4[lane * 16 + q];
    Wreg[4 * q + 0] = w.x; Wreg[4 * q + 1] = w.y;
    Wreg[4 * q + 2] = w.z; Wreg[4 * q + 3] = w.w;
  }
  #pragma unroll
  for (int k = 0; k < 64; ++k) asm volatile("" : "+v"(Wreg[k]));

  // this wave's 64 reactions: rbase + 0..63
  int rbase = R0 + wv * 64;
  int o0l = off_s[wv * 64 + lane];
  int o1l = off_s[wv * 64 + lane + 1];
  float lkl = (rbase + lane < N_RXN) ? log_k[rbase + lane] : 0.f;
  float vmine = 0.f;

  __syncthreads();

  #pragma clang loop unroll(disable)
  for (int i = 0; i < 64; ++i) {
    if (rbase + i >= N_RXN) break;  // uniform
    int o0 = bcast_i(o0l, i), o1 = bcast_i(o1l, i);
    if (fits) {
      process_rxn(i, lane, o0, o1, estart, (const float2*)scs, (const int*)sm,
                  w1x, w1y, b1j, bwj, b3j, w4j, b40, Wreg, lkl, &vmine, total);
    } else {
      process_rxn(i, lane, o0, o1, estart, cs_sorted + estart, m_sorted + estart,
                  w1x, w1y, b1j, bwj, b3j, w4j, b40, Wreg, lkl, &vmine, total);
    }
  }

  if (rbase + lane < N_RXN) vr[rbase + lane].x = vmine;  // coalesced-ish strided store
}

__global__ void k_scale(const float* __restrict__ total, const float* __restrict__ x,
                        float* __restrict__ met_scale) {
  int m = blockIdx.x * blockDim.x + threadIdx.x;
  if (m < N_MET) {
    float tot = total[m];
    float cc = x[m * 8 + 3];
    met_scale[m] = (tot > 1e-12f) ? fminf(cc / tot, 1.0f) : 1.0f;
  }
}

// edge-parallel rxn_scale: uint atomicMin == float min for positive floats
__global__ void k_minscale(const int* __restrict__ met_sub, const int* __restrict__ rxn_sub,
                           const float* __restrict__ met_scale, float2* __restrict__ vr) {
  int e = blockIdx.x * blockDim.x + threadIdx.x;
  if (e < E_SUB) {
    unsigned s = __float_as_uint(met_scale[met_sub[e]]);
    atomicMin((unsigned*)&vr[rxn_sub[e]].y, s);
  }
}

__global__ void k_contrib(const int* __restrict__ met_all, const int* __restrict__ rxn_all,
                          const float* __restrict__ sto_all, const float2* __restrict__ vr,
                          float* __restrict__ dxdt) {
  int t = blockIdx.x * blockDim.x + threadIdx.x;
  if (t < E_ALL / 4) {
    int4 me = ((const int4*)met_all)[t];
    int4 re = ((const int4*)rxn_all)[t];
    float4 se = ((const float4*)sto_all)[t];
    float2 g0 = vr[re.x], g1 = vr[re.y], g2 = vr[re.z], g3 = vr[re.w];
    atomic_add_f32(&dxdt[me.x], se.x * g0.x * g0.y);
    atomic_add_f32(&dxdt[me.y], se.y * g1.x * g1.y);
    atomic_add_f32(&dxdt[me.z], se.z * g2.x * g2.y);
    atomic_add_f32(&dxdt[me.w], se.w * g3.x * g3.y);
  }
}

extern "C" void kernel_launch(void* const* d_in, const int* in_sizes, int n_in,
                              void* d_out, int out_size, void* d_ws, size_t ws_size,
                              hipStream_t stream) {
  const float* x       = (const float*)d_in[0];
  const int*   met_sub = (const int*)d_in[1];
  const int*   rxn_sub = (const int*)d_in[2];
  const float* sto_sub = (const float*)d_in[3];
  const int*   met_all = (const int*)d_in[4];
  const int*   rxn_all = (const int*)d_in[5];
  const float* sto_all = (const float*)d_in[6];
  const float* W1    = (const float*)d_in[7];
  const float* b1    = (const float*)d_in[8];
  const float* W2    = (const float*)d_in[9];
  const float* b2    = (const float*)d_in[10];
  const float* W3    = (const float*)d_in[11];
  const float* b3    = (const float*)d_in[12];
  const float* W4    = (const float*)d_in[13];
  const float* b4    = (const float*)d_in[14];
  const float* log_k = (const float*)d_in[15];
  float* dxdt = (float*)d_out;

  char* ws = (char*)d_ws;
  size_t p = 0;
  auto alloc = [&](size_t bytes) -> void* {
    void* r = (void*)(ws + p);
    p += (bytes + 255) & ~(size_t)255;
    return r;
  };
  int*    counts    = (int*)alloc(sizeof(int) * N_RXN);
  int*    off       = (int*)alloc(sizeof(int) * (N_RXN + 1));
  int*    cursor    = (int*)alloc(sizeof(int) * N_RXN);
  int*    bsums     = (int*)alloc(sizeof(int) * 1024);
  float*  Wt        = (float*)alloc(sizeof(float) * 4096);
  float*  b2w3      = (float*)alloc(sizeof(float) * 64);
  float2* vr        = (float2*)alloc(sizeof(float2) * N_RXN);  // .x = v_pre, .y = scale
  float*  total     = (float*)alloc(sizeof(float) * N_MET);
  float*  met_scale = (float*)alloc(sizeof(float) * N_MET);
  int*    m_sorted  = (int*)alloc(sizeof(int) * E_SUB);
  float2* cs_sorted = (float2*)alloc(sizeof(float2) * E_SUB);
  (void)ws_size; (void)in_sizes; (void)n_in; (void)out_size;

  hipMemsetAsync(counts, 0, sizeof(int) * N_RXN, stream);
  hipMemsetAsync(total, 0, sizeof(float) * N_MET, stream);
  hipMemsetAsync(dxdt, 0, sizeof(float) * N_MET, stream);

  k_pre<<<16, 256, 0, stream>>>(W2, W3, b2, Wt, b2w3);
  k_hist<<<(E_SUB / 4 + 255) / 256, 256, 0, stream>>>(rxn_sub, counts);
  k_scan1<<<SCAN_NB, SCAN_T, 0, stream>>>(counts, bsums);
  k_scan2<<<1, SCAN_T, 0, stream>>>(bsums);
  k_scan3<<<SCAN_NB, SCAN_T, 0, stream>>>(counts, bsums, off, cursor, vr);
  k_scatter<<<(E_SUB + 255) / 256, 256, 0, stream>>>(rxn_sub, met_sub, sto_sub, x,
                                                     cursor, m_sorted, cs_sorted);
  k_rxn<<<(N_RXN + RXN_PER_BLK - 1) / RXN_PER_BLK, 256, 0, stream>>>(
      off, m_sorted, cs_sorted, W1, b1, Wt, b2w3, b3, W4, b4, log_k, vr, total);
  k_scale<<<(N_MET + 255) / 256, 256, 0, stream>>>(total, x, met_scale);
  k_minscale<<<(E_SUB + 255) / 256, 256, 0, stream>>>(met_sub, rxn_sub, met_scale, vr);
  k_contrib<<<(E_ALL / 4 + 255) / 256, 256, 0, stream>>>(met_all, rxn_all, sto_all, vr, dxdt);
}

// Round 4
// 911.887 us; speedup vs baseline: 1.2455x; 1.0402x over previous
//
#include <hip/hip_runtime.h>

#define N_MET 250000
#define N_RXN 500000
#define E_SUB 2000000
#define E_ALL 4000000
#define DT 0.01f

#define RXN_PER_BLK 128
#define THREADS 128
#define EDGE_CAP 768   // sum of 128 Poisson(4) = Poisson(512), cap = +11 sigma; fallback path below

#define SCAN_T 256
#define SCAN_V 8
#define SCAN_CHUNK (SCAN_T * SCAN_V)
#define SCAN_NB ((N_RXN + SCAN_CHUNK - 1) / SCAN_CHUNK)
static_assert(SCAN_NB <= SCAN_T, "scan2 single block must cover all block sums");

typedef int v4i __attribute__((ext_vector_type(4)));
typedef float v4f __attribute__((ext_vector_type(4)));

static __device__ __forceinline__ float fast_tanh(float x) {
  float e = __expf(x + x);
  return 1.0f - __fdividef(2.0f, e + 1.0f);
}

static __device__ __forceinline__ void atomic_add_f32(float* p, float v) {
  __hip_atomic_fetch_add(p, v, __ATOMIC_RELAXED, __HIP_MEMORY_SCOPE_AGENT);
}

static __device__ __forceinline__ float bcast_f(float v, int lane) {
  return __builtin_bit_cast(float, __builtin_amdgcn_readlane(__builtin_bit_cast(int, v), lane));
}
static __device__ __forceinline__ int bcast_i(int v, int lane) {
  return __builtin_amdgcn_readlane(v, lane);
}

// ---- precompute W23t[j][i] = (W2@W3)[i][j] and b2@W3 ----
__global__ void k_pre(const float* __restrict__ W2, const float* __restrict__ W3,
                      const float* __restrict__ b2, float* __restrict__ Wt,
                      float* __restrict__ b2w3) {
  int idx = blockIdx.x * blockDim.x + threadIdx.x;
  if (idx < 4096) {
    int j = idx >> 6, i = idx & 63;
    float s = 0.f;
    #pragma unroll
    for (int k = 0; k < 32; ++k) s = fmaf(W2[i * 32 + k], W3[k * 64 + j], s);
    Wt[j * 64 + i] = s;
    if (i == 0) {
      float t = 0.f;
      #pragma unroll
      for (int k = 0; k < 32; ++k) t = fmaf(b2[k], W3[k * 64 + j], t);
      b2w3[j] = t;
    }
  }
}

// ---- CSR build ----
__global__ void k_hist(const int* __restrict__ rxn_sub, int* __restrict__ counts) {
  int t = blockIdx.x * blockDim.x + threadIdx.x;
  if (t < E_SUB / 4) {
    int4 r = ((const int4*)rxn_sub)[t];
    atomicAdd(&counts[r.x], 1);
    atomicAdd(&counts[r.y], 1);
    atomicAdd(&counts[r.z], 1);
    atomicAdd(&counts[r.w], 1);
  }
}

__global__ void k_scan1(const int* __restrict__ counts, int* __restrict__ bsums) {
  __shared__ int ss[SCAN_T];
  int b = blockIdx.x, t = threadIdx.x;
  int base = b * SCAN_CHUNK + t * SCAN_V;
  int s = 0;
  #pragma unroll
  for (int k = 0; k < SCAN_V; ++k) { int i = base + k; if (i < N_RXN) s += counts[i]; }
  ss[t] = s; __syncthreads();
  for (int d = SCAN_T / 2; d > 0; d >>= 1) {
    if (t < d) ss[t] += ss[t + d];
    __syncthreads();
  }
  if (t == 0) bsums[b] = ss[0];
}

__global__ void k_scan2(int* __restrict__ bsums) {
  __shared__ int ss[SCAN_T];
  int t = threadIdx.x;
  int v = (t < SCAN_NB) ? bsums[t] : 0;
  ss[t] = v; __syncthreads();
  for (int d = 1; d < SCAN_T; d <<= 1) {
    int a = (t >= d) ? ss[t - d] : 0;
    __syncthreads();
    ss[t] += a;
    __syncthreads();
  }
  if (t < SCAN_NB) bsums[t] = ss[t] - v;  // exclusive
}

__global__ void k_scan3(const int* __restrict__ counts, const int* __restrict__ bsums,
                        int* __restrict__ off, int* __restrict__ cursor,
                        float2* __restrict__ vr) {
  __shared__ int ss[SCAN_T];
  int b = blockIdx.x, t = threadIdx.x;
  int base = b * SCAN_CHUNK + t * SCAN_V;
  int v[SCAN_V];
  int s = 0;
  #pragma unroll
  for (int k = 0; k < SCAN_V; ++k) { int i = base + k; v[k] = (i < N_RXN) ? counts[i] : 0; s += v[k]; }
  ss[t] = s; __syncthreads();
  for (int d = 1; d < SCAN_T; d <<= 1) {
    int a = (t >= d) ? ss[t - d] : 0;
    __syncthreads();
    ss[t] += a;
    __syncthreads();
  }
  int run = bsums[b] + ss[t] - s;
  #pragma unroll
  for (int k = 0; k < SCAN_V; ++k) {
    int i = base + k;
    if (i < N_RXN) {
      off[i] = run; cursor[i] = run;
      vr[i] = make_float2(0.f, 1.0f);  // .y = scale accumulator (uint-min on positive floats)
    }
    run += v[k];
  }
  if (b == 0 && t == 0) off[N_RXN] = E_SUB;
}

// ---- scatter into CSR order: ONE 16B record per edge {conc, sto, bitcast(m), 0} ----
__global__ void k_scatter(const int* __restrict__ rxn_sub, const int* __restrict__ met_sub,
                          const float* __restrict__ sto_sub, const float* __restrict__ x,
                          int* __restrict__ cursor, float4* __restrict__ edges) {
  int e = blockIdx.x * blockDim.x + threadIdx.x;
  if (e < E_SUB) {
    int r = rxn_sub[e];
    int pos = atomicAdd(&cursor[r], 1);
    int m = met_sub[e];
    edges[pos] = make_float4(x[m * 8 + 3], sto_sub[e], __int_as_float(m), 0.f);
  }
}

// Per-reaction body; ep points into LDS (fast path) or global (fallback); indices rel. estart.
template <typename EP>
static __device__ __forceinline__ void process_rxn(
    int i, int lane, int o0, int o1, int estart, EP ep,
    float w1x, float w1y, float b1j, float bwj, float b3j, float w4j, float b40,
    const float* Wreg, float lkl, float* vmine, float* __restrict__ total) {
  // edge phase: 2 accumulators to shorten the tanh dependency chain
  float T0 = 0.f, T1 = 0.f;
  int c = o0;
  for (; c + 1 < o1; c += 2) {
    float4 e0 = ep[c - estart];
    float4 e1 = ep[c + 1 - estart];
    T0 += fast_tanh(fmaf(e0.x, w1x, fmaf(e0.y, w1y, b1j)));
    T1 += fast_tanh(fmaf(e1.x, w1x, fmaf(e1.y, w1y, b1j)));
  }
  if (c < o1) {
    float4 e0 = ep[c - estart];
    T0 += fast_tanh(fmaf(e0.x, w1x, fmaf(e0.y, w1y, b1j)));
  }
  float T = T0 + T1;

  // matvec: u_j = n*b2w3_j + b3_j + sum_k T_k * W23t[j][k]; 4 accumulators
  float n = (float)(o1 - o0);
  float u0 = fmaf(n, bwj, b3j), u1 = 0.f, u2 = 0.f, u3 = 0.f;
  #pragma unroll
  for (int k = 0; k < 64; k += 4) {
    u0 = fmaf(bcast_f(T, k + 0), Wreg[k + 0], u0);
    u1 = fmaf(bcast_f(T, k + 1), Wreg[k + 1], u1);
    u2 = fmaf(bcast_f(T, k + 2), Wreg[k + 2], u2);
    u3 = fmaf(bcast_f(T, k + 3), Wreg[k + 3], u3);
  }
  float u = (u0 + u1) + (u2 + u3);

  float z = fast_tanh(u) * w4j;
  #pragma unroll
  for (int d = 32; d > 0; d >>= 1) z += __shfl_xor(z, d, 64);
  float racc = z + b40;

  float k10 = __expf(bcast_f(lkl, i) * 2.3025850929940457f);
  float sp = (racc > 15.f) ? racc : __logf(1.f + __expf(racc));
  float v = k10 * sp;
  *vmine = (lane == i) ? v : *vmine;

  float vdt = v * DT;
  for (int c2 = o0 + lane; c2 < o1; c2 += 64) {
    float4 ee = ep[c2 - estart];
    atomic_add_f32(&total[__float_as_int(ee.z)], ee.y * vdt);
  }
}

// ---- wave-per-reaction with block-level LDS staging ----
__global__ __launch_bounds__(THREADS) void k_rxn(
    const int* __restrict__ off, const float4* __restrict__ edges,
    const float* __restrict__ W1, const float* __restrict__ b1,
    const float* __restrict__ Wt, const float* __restrict__ b2w3,
    const float* __restrict__ b3, const float* __restrict__ W4,
    const float* __restrict__ b4, const float* __restrict__ log_k,
    float2* __restrict__ vr, float* __restrict__ total) {
  __shared__ int off_s[RXN_PER_BLK + 1];
  __shared__ float4 se[EDGE_CAP];

  int tid = threadIdx.x;
  int lane = tid & 63;
  int wv = tid >> 6;
  int R0 = blockIdx.x * RXN_PER_BLK;

  for (int i = tid; i <= RXN_PER_BLK; i += THREADS) {
    int r = R0 + i;
    off_s[i] = off[r > N_RXN ? N_RXN : r];
  }
  __syncthreads();
  int estart = off_s[0];
  int nE = off_s[RXN_PER_BLK] - estart;
  bool fits = (nE <= EDGE_CAP);
  if (fits) {
    for (int i = tid; i < nE; i += THREADS) se[i] = edges[estart + i];
  }

  float w1x = W1[lane], w1y = W1[64 + lane], b1j = b1[lane];
  float bwj = b2w3[lane], b3j = b3[lane], w4j = W4[lane];
  float b40 = b4[0];
  float Wreg[64];
  const float4* Wt4 = (const float4*)Wt;
  #pragma unroll
  for (int q = 0; q < 16; ++q) {
    float4 w = Wt4[lane * 16 + q];
    Wreg[4 * q + 0] = w.x; Wreg[4 * q + 1] = w.y;
    Wreg[4 * q + 2] = w.z; Wreg[4 * q + 3] = w.w;
  }
  #pragma unroll
  for (int k = 0; k < 64; ++k) asm volatile("" : "+v"(Wreg[k]));

  int rbase = R0 + wv * 64;
  int o0l = off_s[wv * 64 + lane];
  int o1l = off_s[wv * 64 + lane + 1];
  float lkl = (rbase + lane < N_RXN) ? log_k[rbase + lane] : 0.f;
  float vmine = 0.f;

  __syncthreads();

  #pragma clang loop unroll(disable)
  for (int i = 0; i < 64; ++i) {
    if (rbase + i >= N_RXN) break;  // uniform
    int o0 = bcast_i(o0l, i), o1 = bcast_i(o1l, i);
    if (fits) {
      process_rxn(i, lane, o0, o1, estart, (const float4*)se,
                  w1x, w1y, b1j, bwj, b3j, w4j, b40, Wreg, lkl, &vmine, total);
    } else {
      process_rxn(i, lane, o0, o1, estart, edges + estart,
                  w1x, w1y, b1j, bwj, b3j, w4j, b40, Wreg, lkl, &vmine, total);
    }
  }

  if (rbase + lane < N_RXN) vr[rbase + lane].x = vmine;
}

__global__ void k_scale(const float* __restrict__ total, const float* __restrict__ x,
                        float* __restrict__ met_scale) {
  int m = blockIdx.x * blockDim.x + threadIdx.x;
  if (m < N_MET) {
    float tot = total[m];
    float cc = x[m * 8 + 3];
    met_scale[m] = (tot > 1e-12f) ? fminf(cc / tot, 1.0f) : 1.0f;
  }
}

// edge-parallel rxn_scale: uint atomicMin == float min for positive floats
__global__ void k_minscale(const int* __restrict__ met_sub, const int* __restrict__ rxn_sub,
                           const float* __restrict__ met_scale, float2* __restrict__ vr) {
  int e = blockIdx.x * blockDim.x + threadIdx.x;
  if (e < E_SUB) {
    unsigned s = __float_as_uint(met_scale[met_sub[e]]);
    atomicMin((unsigned*)&vr[rxn_sub[e]].y, s);
  }
}

__global__ void k_vmul(const float2* __restrict__ vr, float* __restrict__ vfin) {
  int r = blockIdx.x * blockDim.x + threadIdx.x;
  if (r < N_RXN) {
    float2 g = vr[r];
    vfin[r] = g.x * g.y;
  }
}

__global__ void k_contrib(const int* __restrict__ met_all, const int* __restrict__ rxn_all,
                          const float* __restrict__ sto_all, const float* __restrict__ vfin,
                          float* __restrict__ dxdt) {
  int t = blockIdx.x * blockDim.x + threadIdx.x;
  if (t < E_ALL / 4) {
    // nontemporal loads: keep vfin/dxdt L2-resident while streaming 48 MB past them
    v4i me = __builtin_nontemporal_load((const v4i*)met_all + t);
    v4i re = __builtin_nontemporal_load((const v4i*)rxn_all + t);
    v4f se = __builtin_nontemporal_load((const v4f*)sto_all + t);
    atomic_add_f32(&dxdt[me.x], se.x * vfin[re.x]);
    atomic_add_f32(&dxdt[me.y], se.y * vfin[re.y]);
    atomic_add_f32(&dxdt[me.z], se.z * vfin[re.z]);
    atomic_add_f32(&dxdt[me.w], se.w * vfin[re.w]);
  }
}

extern "C" void kernel_launch(void* const* d_in, const int* in_sizes, int n_in,
                              void* d_out, int out_size, void* d_ws, size_t ws_size,
                              hipStream_t stream) {
  const float* x       = (const float*)d_in[0];
  const int*   met_sub = (const int*)d_in[1];
  const int*   rxn_sub = (const int*)d_in[2];
  const float* sto_sub = (const float*)d_in[3];
  const int*   met_all = (const int*)d_in[4];
  const int*   rxn_all = (const int*)d_in[5];
  const float* sto_all = (const float*)d_in[6];
  const float* W1    = (const float*)d_in[7];
  const float* b1    = (const float*)d_in[8];
  const float* W2    = (const float*)d_in[9];
  const float* b2    = (const float*)d_in[10];
  const float* W3    = (const float*)d_in[11];
  const float* b3    = (const float*)d_in[12];
  const float* W4    = (const float*)d_in[13];
  const float* b4    = (const float*)d_in[14];
  const float* log_k = (const float*)d_in[15];
  float* dxdt = (float*)d_out;

  char* ws = (char*)d_ws;
  size_t p = 0;
  auto alloc = [&](size_t bytes) -> void* {
    void* r = (void*)(ws + p);
    p += (bytes + 255) & ~(size_t)255;
    return r;
  };
  int*    counts    = (int*)alloc(sizeof(int) * N_RXN);
  int*    off       = (int*)alloc(sizeof(int) * (N_RXN + 1));
  int*    cursor    = (int*)alloc(sizeof(int) * N_RXN);
  int*    bsums     = (int*)alloc(sizeof(int) * 1024);
  float*  Wt        = (float*)alloc(sizeof(float) * 4096);
  float*  b2w3      = (float*)alloc(sizeof(float) * 64);
  float2* vr        = (float2*)alloc(sizeof(float2) * N_RXN);   // .x = v_pre, .y = scale
  float*  vfin      = (float*)alloc(sizeof(float) * N_RXN);
  float*  total     = (float*)alloc(sizeof(float) * N_MET);
  float*  met_scale = (float*)alloc(sizeof(float) * N_MET);
  float4* edges     = (float4*)alloc(sizeof(float4) * E_SUB);   // {conc, sto, m, -} CSR-ordered
  (void)ws_size; (void)in_sizes; (void)n_in; (void)out_size;

  hipMemsetAsync(counts, 0, sizeof(int) * N_RXN, stream);
  hipMemsetAsync(total, 0, sizeof(float) * N_MET, stream);
  hipMemsetAsync(dxdt, 0, sizeof(float) * N_MET, stream);

  k_pre<<<16, 256, 0, stream>>>(W2, W3, b2, Wt, b2w3);
  k_hist<<<(E_SUB / 4 + 255) / 256, 256, 0, stream>>>(rxn_sub, counts);
  k_scan1<<<SCAN_NB, SCAN_T, 0, stream>>>(counts, bsums);
  k_scan2<<<1, SCAN_T, 0, stream>>>(bsums);
  k_scan3<<<SCAN_NB, SCAN_T, 0, stream>>>(counts, bsums, off, cursor, vr);
  k_scatter<<<(E_SUB + 255) / 256, 256, 0, stream>>>(rxn_sub, met_sub, sto_sub, x,
                                                     cursor, edges);
  k_rxn<<<(N_RXN + RXN_PER_BLK - 1) / RXN_PER_BLK, THREADS, 0, stream>>>(
      off, edges, W1, b1, Wt, b2w3, b3, W4, b4, log_k, vr, total);
  k_scale<<<(N_MET + 255) / 256, 256, 0, stream>>>(total, x, met_scale);
  k_minscale<<<(E_SUB + 255) / 256, 256, 0, stream>>>(met_sub, rxn_sub, met_scale, vr);
  k_vmul<<<(N_RXN + 255) / 256, 256, 0, stream>>>(vr, vfin);
  k_contrib<<<(E_ALL / 4 + 255) / 256, 256, 0, stream>>>(met_all, rxn_all, sto_all, vfin, dxdt);
}

// Round 5
// 834.804 us; speedup vs baseline: 1.3605x; 1.0923x over previous
//
#include <hip/hip_runtime.h>

#define N_MET 250000
#define N_RXN 500000
#define E_SUB 2000000
#define E_ALL 4000000
#define DT 0.01f

#define RXN_PER_BLK 128
#define THREADS 128
#define EDGE_CAP 768   // sum of 128 Poisson(4) = Poisson(512); +11 sigma; fallback path below

#define SCAN_T 256
#define SCAN_V 8
#define SCAN_CHUNK (SCAN_T * SCAN_V)
#define SCAN_NB ((N_RXN + SCAN_CHUNK - 1) / SCAN_CHUNK)
static_assert(SCAN_NB <= SCAN_T, "scan2 single block must cover all block sums");

typedef int v4i __attribute__((ext_vector_type(4)));
typedef float v4f __attribute__((ext_vector_type(4)));

static __device__ __forceinline__ float fast_tanh(float x) {
  float e = __expf(x + x);
  return 1.0f - __fdividef(2.0f, e + 1.0f);
}

static __device__ __forceinline__ void atomic_add_f32(float* p, float v) {
  __hip_atomic_fetch_add(p, v, __ATOMIC_RELAXED, __HIP_MEMORY_SCOPE_AGENT);
}

static __device__ __forceinline__ float bcast_f(float v, int lane) {
  return __builtin_bit_cast(float, __builtin_amdgcn_readlane(__builtin_bit_cast(int, v), lane));
}
static __device__ __forceinline__ int bcast_i(int v, int lane) {
  return __builtin_amdgcn_readlane(v, lane);
}

// ---- precompute W23t[j][i] = (W2@W3)[i][j] and b2@W3 ----
__global__ void k_pre(const float* __restrict__ W2, const float* __restrict__ W3,
                      const float* __restrict__ b2, float* __restrict__ Wt,
                      float* __restrict__ b2w3) {
  int idx = blockIdx.x * blockDim.x + threadIdx.x;
  if (idx < 4096) {
    int j = idx >> 6, i = idx & 63;
    float s = 0.f;
    #pragma unroll
    for (int k = 0; k < 32; ++k) s = fmaf(W2[i * 32 + k], W3[k * 64 + j], s);
    Wt[j * 64 + i] = s;
    if (i == 0) {
      float t = 0.f;
      #pragma unroll
      for (int k = 0; k < 32; ++k) t = fmaf(b2[k], W3[k * 64 + j], t);
      b2w3[j] = t;
    }
  }
}

// ---- histogram + dense conc extraction (conc[m] = x[m*8+3]) ----
__global__ void k_hist(const int* __restrict__ rxn_sub, const float* __restrict__ x,
                       int* __restrict__ counts, float* __restrict__ conc) {
  int t = blockIdx.x * blockDim.x + threadIdx.x;
  if (t < E_SUB / 4) {
    v4i r = __builtin_nontemporal_load((const v4i*)rxn_sub + t);
    atomicAdd(&counts[r.x], 1);
    atomicAdd(&counts[r.y], 1);
    atomicAdd(&counts[r.z], 1);
    atomicAdd(&counts[r.w], 1);
  }
  if (t < N_MET) conc[t] = __builtin_nontemporal_load(x + t * 8 + 3);
}

__global__ void k_scan1(const int* __restrict__ counts, int* __restrict__ bsums) {
  __shared__ int ss[SCAN_T];
  int b = blockIdx.x, t = threadIdx.x;
  int base = b * SCAN_CHUNK + t * SCAN_V;
  int s = 0;
  #pragma unroll
  for (int k = 0; k < SCAN_V; ++k) { int i = base + k; if (i < N_RXN) s += counts[i]; }
  ss[t] = s; __syncthreads();
  for (int d = SCAN_T / 2; d > 0; d >>= 1) {
    if (t < d) ss[t] += ss[t + d];
    __syncthreads();
  }
  if (t == 0) bsums[b] = ss[0];
}

__global__ void k_scan2(int* __restrict__ bsums) {
  __shared__ int ss[SCAN_T];
  int t = threadIdx.x;
  int v = (t < SCAN_NB) ? bsums[t] : 0;
  ss[t] = v; __syncthreads();
  for (int d = 1; d < SCAN_T; d <<= 1) {
    int a = (t >= d) ? ss[t - d] : 0;
    __syncthreads();
    ss[t] += a;
    __syncthreads();
  }
  if (t < SCAN_NB) bsums[t] = ss[t] - v;  // exclusive
}

__global__ void k_scan3(const int* __restrict__ counts, const int* __restrict__ bsums,
                        int* __restrict__ off, int* __restrict__ cursor,
                        float2* __restrict__ vr) {
  __shared__ int ss[SCAN_T];
  int b = blockIdx.x, t = threadIdx.x;
  int base = b * SCAN_CHUNK + t * SCAN_V;
  int v[SCAN_V];
  int s = 0;
  #pragma unroll
  for (int k = 0; k < SCAN_V; ++k) { int i = base + k; v[k] = (i < N_RXN) ? counts[i] : 0; s += v[k]; }
  ss[t] = s; __syncthreads();
  for (int d = 1; d < SCAN_T; d <<= 1) {
    int a = (t >= d) ? ss[t - d] : 0;
    __syncthreads();
    ss[t] += a;
    __syncthreads();
  }
  int run = bsums[b] + ss[t] - s;
  #pragma unroll
  for (int k = 0; k < SCAN_V; ++k) {
    int i = base + k;
    if (i < N_RXN) {
      off[i] = run; cursor[i] = run;
      vr[i] = make_float2(0.f, 1.0f);  // .y = scale accumulator (uint-min on positive floats)
    }
    run += v[k];
  }
  if (b == 0 && t == 0) off[N_RXN] = E_SUB;
}

// ---- scatter into CSR order: ONE 16B record per edge {conc, sto, bitcast(m), 0} ----
__global__ void k_scatter(const int* __restrict__ rxn_sub, const int* __restrict__ met_sub,
                          const float* __restrict__ sto_sub, const float* __restrict__ conc,
                          int* __restrict__ cursor, float4* __restrict__ edges) {
  int e = blockIdx.x * blockDim.x + threadIdx.x;
  if (e < E_SUB) {
    int r = __builtin_nontemporal_load(rxn_sub + e);
    int m = __builtin_nontemporal_load(met_sub + e);
    float st = __builtin_nontemporal_load(sto_sub + e);
    int pos = atomicAdd(&cursor[r], 1);
    edges[pos] = make_float4(conc[m], st, __int_as_float(m), 0.f);
  }
}

// Per-reaction body; ep points into LDS (fast path) or global (fallback); indices rel. estart.
// sTslot: wave-private 64-float LDS slot for broadcasting T across lanes.
template <typename EP>
static __device__ __forceinline__ void process_rxn(
    int i, int lane, int o0, int o1, int estart, EP ep, float* sTslot,
    float w1x, float w1y, float b1j, float bwj, float b3j, float w4j, float b40,
    const float* Wreg, float lkl, float* vmine, float* __restrict__ total) {
  // edge phase: 2 accumulators to shorten the tanh dependency chain
  float T0 = 0.f, T1 = 0.f;
  int c = o0;
  for (; c + 1 < o1; c += 2) {
    float4 e0 = ep[c - estart];
    float4 e1 = ep[c + 1 - estart];
    T0 += fast_tanh(fmaf(e0.x, w1x, fmaf(e0.y, w1y, b1j)));
    T1 += fast_tanh(fmaf(e1.x, w1x, fmaf(e1.y, w1y, b1j)));
  }
  if (c < o1) {
    float4 e0 = ep[c - estart];
    T0 += fast_tanh(fmaf(e0.x, w1x, fmaf(e0.y, w1y, b1j)));
  }
  float T = T0 + T1;

  // broadcast T via wave-private LDS slot (replaces 64 v_readlane)
  sTslot[lane] = T;
  const float4* sT4 = (const float4*)sTslot;

  // matvec: u_j = n*b2w3_j + b3_j + sum_k T_k * W23t[j][k]; 4 accumulators, 64 fma
  float n = (float)(o1 - o0);
  float u0 = fmaf(n, bwj, b3j), u1 = 0.f, u2 = 0.f, u3 = 0.f;
  #pragma unroll
  for (int q = 0; q < 16; ++q) {
    float4 t = sT4[q];  // same-address broadcast read, conflict-free
    u0 = fmaf(t.x, Wreg[4 * q + 0], u0);
    u1 = fmaf(t.y, Wreg[4 * q + 1], u1);
    u2 = fmaf(t.z, Wreg[4 * q + 2], u2);
    u3 = fmaf(t.w, Wreg[4 * q + 3], u3);
  }
  float u = (u0 + u1) + (u2 + u3);

  float z = fast_tanh(u) * w4j;
  #pragma unroll
  for (int d = 32; d > 0; d >>= 1) z += __shfl_xor(z, d, 64);
  float racc = z + b40;

  float k10 = __expf(bcast_f(lkl, i) * 2.3025850929940457f);
  float sp = (racc > 15.f) ? racc : __logf(1.f + __expf(racc));
  float v = k10 * sp;
  *vmine = (lane == i) ? v : *vmine;

  float vdt = v * DT;
  for (int c2 = o0 + lane; c2 < o1; c2 += 64) {
    float4 ee = ep[c2 - estart];
    atomic_add_f32(&total[__float_as_int(ee.z)], ee.y * vdt);
  }
}

// ---- wave-per-reaction with block-level LDS staging ----
// launch_bounds(128, 4): min 4 waves/EU -> VGPR cap 128, enough for Wreg[64] resident.
__global__ __launch_bounds__(THREADS, 4) void k_rxn(
    const int* __restrict__ off, const float4* __restrict__ edges,
    const float* __restrict__ W1, const float* __restrict__ b1,
    const float* __restrict__ Wt, const float* __restrict__ b2w3,
    const float* __restrict__ b3, const float* __restrict__ W4,
    const float* __restrict__ b4, const float* __restrict__ log_k,
    float2* __restrict__ vr, float* __restrict__ total) {
  __shared__ int off_s[RXN_PER_BLK + 1];
  __shared__ float4 se[EDGE_CAP];
  __shared__ float sT[THREADS];  // per-wave 64-float broadcast slots

  int tid = threadIdx.x;
  int lane = tid & 63;
  int wv = tid >> 6;
  int R0 = blockIdx.x * RXN_PER_BLK;

  for (int i = tid; i <= RXN_PER_BLK; i += THREADS) {
    int r = R0 + i;
    off_s[i] = off[r > N_RXN ? N_RXN : r];
  }
  __syncthreads();
  int estart = off_s[0];
  int nE = off_s[RXN_PER_BLK] - estart;
  bool fits = (nE <= EDGE_CAP);
  if (fits) {
    for (int i = tid; i < nE; i += THREADS) se[i] = edges[estart + i];
  }

  float w1x = W1[lane], w1y = W1[64 + lane], b1j = b1[lane];
  float bwj = b2w3[lane], b3j = b3[lane], w4j = W4[lane];
  float b40 = b4[0];
  float Wreg[64];  // row j of W23t; VGPR-resident under the 128-reg cap
  const float4* Wt4 = (const float4*)Wt;
  #pragma unroll
  for (int q = 0; q < 16; ++q) {
    float4 w = Wt4[lane * 16 + q];
    Wreg[4 * q + 0] = w.x; Wreg[4 * q + 1] = w.y;
    Wreg[4 * q + 2] = w.z; Wreg[4 * q + 3] = w.w;
  }

  int rbase = R0 + wv * 64;
  int o0l = off_s[wv * 64 + lane];
  int o1l = off_s[wv * 64 + lane + 1];
  float lkl = (rbase + lane < N_RXN) ? log_k[rbase + lane] : 0.f;
  float vmine = 0.f;
  float* sTslot = &sT[wv * 64];

  __syncthreads();

  #pragma clang loop unroll(disable)
  for (int i = 0; i < 64; ++i) {
    if (rbase + i >= N_RXN) break;  // uniform
    int o0 = bcast_i(o0l, i), o1 = bcast_i(o1l, i);
    if (fits) {
      process_rxn(i, lane, o0, o1, estart, (const float4*)se, sTslot,
                  w1x, w1y, b1j, bwj, b3j, w4j, b40, Wreg, lkl, &vmine, total);
    } else {
      process_rxn(i, lane, o0, o1, estart, edges + estart, sTslot,
                  w1x, w1y, b1j, bwj, b3j, w4j, b40, Wreg, lkl, &vmine, total);
    }
  }

  if (rbase + lane < N_RXN) vr[rbase + lane].x = vmine;
}

__global__ void k_scale(const float* __restrict__ total, const float* __restrict__ conc,
                        float* __restrict__ met_scale) {
  int m = blockIdx.x * blockDim.x + threadIdx.x;
  if (m < N_MET) {
    float tot = total[m];
    float cc = conc[m];
    met_scale[m] = (tot > 1e-12f) ? fminf(cc / tot, 1.0f) : 1.0f;
  }
}

// edge-parallel rxn_scale: uint atomicMin == float min for positive floats
__global__ void k_minscale(const int* __restrict__ met_sub, const int* __restrict__ rxn_sub,
                           const float* __restrict__ met_scale, float2* __restrict__ vr) {
  int e = blockIdx.x * blockDim.x + threadIdx.x;
  if (e < E_SUB) {
    int m = __builtin_nontemporal_load(met_sub + e);
    int r = __builtin_nontemporal_load(rxn_sub + e);
    unsigned s = __float_as_uint(met_scale[m]);
    atomicMin((unsigned*)&vr[r].y, s);
  }
}

__global__ void k_contrib(const int* __restrict__ met_all, const int* __restrict__ rxn_all,
                          const float* __restrict__ sto_all, const float2* __restrict__ vr,
                          float* __restrict__ dxdt) {
  int t = blockIdx.x * blockDim.x + threadIdx.x;
  if (t < E_ALL / 4) {
    v4i me = __builtin_nontemporal_load((const v4i*)met_all + t);
    v4i re = __builtin_nontemporal_load((const v4i*)rxn_all + t);
    v4f se = __builtin_nontemporal_load((const v4f*)sto_all + t);
    float2 g0 = vr[re.x], g1 = vr[re.y], g2 = vr[re.z], g3 = vr[re.w];
    atomic_add_f32(&dxdt[me.x], se.x * g0.x * g0.y);
    atomic_add_f32(&dxdt[me.y], se.y * g1.x * g1.y);
    atomic_add_f32(&dxdt[me.z], se.z * g2.x * g2.y);
    atomic_add_f32(&dxdt[me.w], se.w * g3.x * g3.y);
  }
}

extern "C" void kernel_launch(void* const* d_in, const int* in_sizes, int n_in,
                              void* d_out, int out_size, void* d_ws, size_t ws_size,
                              hipStream_t stream) {
  const float* x       = (const float*)d_in[0];
  const int*   met_sub = (const int*)d_in[1];
  const int*   rxn_sub = (const int*)d_in[2];
  const float* sto_sub = (const float*)d_in[3];
  const int*   met_all = (const int*)d_in[4];
  const int*   rxn_all = (const int*)d_in[5];
  const float* sto_all = (const float*)d_in[6];
  const float* W1    = (const float*)d_in[7];
  const float* b1    = (const float*)d_in[8];
  const float* W2    = (const float*)d_in[9];
  const float* b2    = (const float*)d_in[10];
  const float* W3    = (const float*)d_in[11];
  const float* b3    = (const float*)d_in[12];
  const float* W4    = (const float*)d_in[13];
  const float* b4    = (const float*)d_in[14];
  const float* log_k = (const float*)d_in[15];
  float* dxdt = (float*)d_out;

  char* ws = (char*)d_ws;
  size_t p = 0;
  auto alloc = [&](size_t bytes) -> void* {
    void* r = (void*)(ws + p);
    p += (bytes + 255) & ~(size_t)255;
    return r;
  };
  int*    counts    = (int*)alloc(sizeof(int) * N_RXN);
  int*    off       = (int*)alloc(sizeof(int) * (N_RXN + 1));
  int*    cursor    = (int*)alloc(sizeof(int) * N_RXN);
  int*    bsums     = (int*)alloc(sizeof(int) * 1024);
  float*  Wt        = (float*)alloc(sizeof(float) * 4096);
  float*  b2w3      = (float*)alloc(sizeof(float) * 64);
  float2* vr        = (float2*)alloc(sizeof(float2) * N_RXN);   // .x = v_pre, .y = scale
  float*  conc      = (float*)alloc(sizeof(float) * N_MET);
  float*  total     = (float*)alloc(sizeof(float) * N_MET);
  float*  met_scale = (float*)alloc(sizeof(float) * N_MET);
  float4* edges     = (float4*)alloc(sizeof(float4) * E_SUB);   // {conc, sto, m, -} CSR-ordered
  (void)ws_size; (void)in_sizes; (void)n_in; (void)out_size;

  hipMemsetAsync(counts, 0, sizeof(int) * N_RXN, stream);
  hipMemsetAsync(total, 0, sizeof(float) * N_MET, stream);
  hipMemsetAsync(dxdt, 0, sizeof(float) * N_MET, stream);

  k_pre<<<16, 256, 0, stream>>>(W2, W3, b2, Wt, b2w3);
  k_hist<<<(E_SUB / 4 + 255) / 256, 256, 0, stream>>>(rxn_sub, x, counts, conc);
  k_scan1<<<SCAN_NB, SCAN_T, 0, stream>>>(counts, bsums);
  k_scan2<<<1, SCAN_T, 0, stream>>>(bsums);
  k_scan3<<<SCAN_NB, SCAN_T, 0, stream>>>(counts, bsums, off, cursor, vr);
  k_scatter<<<(E_SUB + 255) / 256, 256, 0, stream>>>(rxn_sub, met_sub, sto_sub, conc,
                                                     cursor, edges);
  k_rxn<<<(N_RXN + RXN_PER_BLK - 1) / RXN_PER_BLK, THREADS, 0, stream>>>(
      off, edges, W1, b1, Wt, b2w3, b3, W4, b4, log_k, vr, total);
  k_scale<<<(N_MET + 255) / 256, 256, 0, stream>>>(total, conc, met_scale);
  k_minscale<<<(E_SUB + 255) / 256, 256, 0, stream>>>(met_sub, rxn_sub, met_scale, vr);
  k_contrib<<<(E_ALL / 4 + 255) / 256, 256, 0, stream>>>(met_all, rxn_all, sto_all, vr, dxdt);
}